// Round 4
// baseline (929.138 us; speedup 1.0000x reference)
//
#include <hip/hip_runtime.h>

typedef __bf16 bf16x8 __attribute__((ext_vector_type(8)));
typedef float  f32x4  __attribute__((ext_vector_type(4)));

#define N_CELLS 8000
#define N_GENES 8000
#define N_REG   20000
#define NF      100
#define KP      128     // padded K (factors) for MFMA
#define NFT     112     // padded factor count for ASr output (7*16)
#define KSPLIT  5       // split-K slices for ASr (625 k-steps = 5*125)

static __device__ __forceinline__ unsigned short f2bf_bits(float f) {
  unsigned u = __builtin_bit_cast(unsigned, f);
  u = (u + 0x7FFFu + ((u >> 16) & 1u)) >> 16;   // RNE
  return (unsigned short)u;
}
static __device__ __forceinline__ __bf16 f2bf(float f) {
  unsigned short h = f2bf_bits(f);
  return __builtin_bit_cast(__bf16, h);
}
static __device__ __forceinline__ float bf2f(unsigned short s) {
  unsigned u = ((unsigned)s) << 16;
  return __builtin_bit_cast(float, u);
}

// ---------------- softmax(row of 100) then T = Srow @ W, bf16 out padded to 128
__global__ void softmax_matT_kernel(const float* __restrict__ C,
                                    const float* __restrict__ W,
                                    unsigned short* __restrict__ outT) {
  __shared__ float red[128];
  __shared__ float srow[NF];
  int i = blockIdx.x, t = threadIdx.x;
  float v = (t < NF) ? C[i * NF + t] : -3.0e38f;
  red[t] = v; __syncthreads();
  #pragma unroll
  for (int s = 64; s > 0; s >>= 1) { if (t < s) red[t] = fmaxf(red[t], red[t + s]); __syncthreads(); }
  float m = red[0]; __syncthreads();
  float e = (t < NF) ? __expf(v - m) : 0.f;
  red[t] = e; __syncthreads();
  #pragma unroll
  for (int s = 64; s > 0; s >>= 1) { if (t < s) red[t] += red[t + s]; __syncthreads(); }
  float inv = 1.f / red[0];
  if (t < NF) srow[t] = e * inv;
  __syncthreads();
  if (t < NF) {
    float acc = 0.f;
    #pragma unroll 4
    for (int k = 0; k < NF; ++k) acc = fmaf(srow[k], W[k * NF + t], acc);
    outT[i * KP + t] = f2bf_bits(acc);
  } else {
    outT[i * KP + t] = 0;
  }
}

// ---------------- softmax only; row-major bf16 [row][128]; optional transposed [112][nrows]
__global__ void softmax_kernel(const float* __restrict__ C,
                               unsigned short* __restrict__ outR,
                               unsigned short* __restrict__ outT, int nrows) {
  __shared__ float red[128];
  int i = blockIdx.x, t = threadIdx.x;
  float v = (t < NF) ? C[i * NF + t] : -3.0e38f;
  red[t] = v; __syncthreads();
  #pragma unroll
  for (int s = 64; s > 0; s >>= 1) { if (t < s) red[t] = fmaxf(red[t], red[t + s]); __syncthreads(); }
  float m = red[0]; __syncthreads();
  float e = (t < NF) ? __expf(v - m) : 0.f;
  red[t] = e; __syncthreads();
  #pragma unroll
  for (int s = 64; s > 0; s >>= 1) { if (t < s) red[t] += red[t + s]; __syncthreads(); }
  float inv = 1.f / red[0];
  unsigned short b = (t < NF) ? f2bf_bits(e * inv) : (unsigned short)0;
  outR[i * KP + t] = b;
  if (outT != nullptr && t < NFT) outT[t * nrows + i] = b;  // rows 100..111 get zeros
}

// ---------------- fused residual SSE: sum((X - Tm@Sm^T - bcol - brow)^2)
// SWAPPED operand roles: MFMA A = Sm (X-cols), B = Tm (X-rows) so each thread's
// 4 acc elems are 4 CONSECUTIVE X columns -> float4 X loads.
// Block tile: 64 rows x 128 cols; 4 waves as 2(row)x2(col); wave tile 32r x 64c.
// grid.x indexes COLUMN blocks (fastest) -> contiguous row-stripe streaming.
__global__ __launch_bounds__(256) void resid_kernel(
    const float* __restrict__ X,
    const unsigned short* __restrict__ Tm,   // [8000][128] bf16 (X-row panels)
    const unsigned short* __restrict__ Sm,   // [N][128]    bf16 (X-col panels)
    const float* __restrict__ bcol,
    const float* __restrict__ brow,
    int N, float* __restrict__ buckets) {
  int t = threadIdx.x;
  int wid = t >> 6, lane = t & 63;
  int lr = lane & 15, lg = lane >> 4;
  int r0 = blockIdx.y * 64 + (wid >> 1) * 32;
  int c0 = blockIdx.x * 128 + (wid & 1) * 64;

  // ---- issue streaming X loads FIRST (float4, in flight during MFMA)
  f32x4 xv[2][4];
  #pragma unroll
  for (int ri = 0; ri < 2; ++ri) {
    int row = r0 + ri * 16 + lr;
    #pragma unroll
    for (int ci = 0; ci < 4; ++ci) {
      int cb = c0 + ci * 16 + lg * 4;
      if (cb < N) xv[ri][ci] = *reinterpret_cast<const f32x4*>(X + (long)row * N + cb);
      else        xv[ri][ci] = f32x4{0.f, 0.f, 0.f, 0.f};
    }
  }

  // ---- rec = Tm @ Sm^T, computed transposed: acc[ci][ri]
  f32x4 zero = {0.f, 0.f, 0.f, 0.f};
  f32x4 acc[4][2] = {{zero, zero}, {zero, zero}, {zero, zero}, {zero, zero}};
  #pragma unroll
  for (int ks = 0; ks < 4; ++ks) {
    bf16x8 a[4], b[2];
    #pragma unroll
    for (int ci = 0; ci < 4; ++ci) {
      int col = c0 + ci * 16 + lr;
      if (col >= N) col = N - 1;   // masked in epilogue
      a[ci] = *reinterpret_cast<const bf16x8*>(Sm + col * KP + ks * 32 + lg * 8);
    }
    #pragma unroll
    for (int ri = 0; ri < 2; ++ri) {
      int row = r0 + ri * 16 + lr;
      b[ri] = *reinterpret_cast<const bf16x8*>(Tm + row * KP + ks * 32 + lg * 8);
    }
    #pragma unroll
    for (int ci = 0; ci < 4; ++ci)
      #pragma unroll
      for (int ri = 0; ri < 2; ++ri)
        acc[ci][ri] = __builtin_amdgcn_mfma_f32_16x16x32_bf16(a[ci], b[ri], acc[ci][ri], 0, 0, 0);
  }

  // ---- epilogue: D row index = X-col (4 consecutive), D col index = X-row
  float br[2];
  #pragma unroll
  for (int ri = 0; ri < 2; ++ri) br[ri] = brow[r0 + ri * 16 + lr];

  float sse = 0.f;
  #pragma unroll
  for (int ci = 0; ci < 4; ++ci) {
    int cb = c0 + ci * 16 + lg * 4;
    if (cb < N) {
      f32x4 bc = *reinterpret_cast<const f32x4*>(bcol + cb);
      #pragma unroll
      for (int ri = 0; ri < 2; ++ri) {
        f32x4 x = xv[ri][ci];
        #pragma unroll
        for (int j = 0; j < 4; ++j) {
          float e = x[j] - acc[ci][ri][j] - bc[j] - br[ri];
          sse = fmaf(e, e, sse);
        }
      }
    }
  }
  #pragma unroll
  for (int off = 32; off > 0; off >>= 1) sse += __shfl_xor(sse, off);
  __shared__ float wsum[4];
  if (lane == 0) wsum[wid] = sse;
  __syncthreads();
  if (t == 0)
    atomicAdd(&buckets[(blockIdx.y * gridDim.x + blockIdx.x) & 63],
              wsum[0] + wsum[1] + wsum[2] + wsum[3]);
}

// ---------------- ASr = A(f32,[8000][20000]) @ Sr via SrT bf16 [112][20000]
// split-K=5, plain stores into per-slice buffers (no atomics).
// 128 threads = 2 waves; each wave: 16 genes x 112 factors.
// grid (250, 5): 250 blocks * 32 genes = 8000 genes.  (round-3 bug: was 500 -> OOB)
__global__ __launch_bounds__(128) void asr_kernel(
    const float* __restrict__ A,
    const unsigned short* __restrict__ SrT,
    float* __restrict__ ASr5) {
  int t = threadIdx.x;
  int w = t >> 6, lane = t & 63;
  int lr = lane & 15, lg = lane >> 4;
  int g0 = blockIdx.x * 32 + w * 16;
  int kbase = blockIdx.y * (N_REG / KSPLIT);

  f32x4 zero = {0.f, 0.f, 0.f, 0.f};
  f32x4 acc[7] = {zero, zero, zero, zero, zero, zero, zero};

  const float* pa0 = A + (long)(g0 + lr) * N_REG + kbase + lg * 8;
  for (int ks = 0; ks < (N_REG / KSPLIT) / 32; ++ks) {
    int k0 = kbase + ks * 32;
    f32x4 v0 = *reinterpret_cast<const f32x4*>(pa0 + ks * 32);
    f32x4 v1 = *reinterpret_cast<const f32x4*>(pa0 + ks * 32 + 4);
    bf16x8 a;
    a[0] = f2bf(v0[0]); a[1] = f2bf(v0[1]); a[2] = f2bf(v0[2]); a[3] = f2bf(v0[3]);
    a[4] = f2bf(v1[0]); a[5] = f2bf(v1[1]); a[6] = f2bf(v1[2]); a[7] = f2bf(v1[3]);
    #pragma unroll
    for (int ni = 0; ni < 7; ++ni) {
      bf16x8 b = *reinterpret_cast<const bf16x8*>(SrT + (ni * 16 + lr) * N_REG + k0 + lg * 8);
      acc[ni] = __builtin_amdgcn_mfma_f32_16x16x32_bf16(a, b, acc[ni], 0, 0, 0);
    }
  }
  // D: row(m=gene) = lg*4+j, col(n=factor) = ni*16+lr
  float* slice = ASr5 + (long)blockIdx.y * (N_GENES * NFT);
  #pragma unroll
  for (int ni = 0; ni < 7; ++ni) {
    int f = ni * 16 + lr;
    #pragma unroll
    for (int j = 0; j < 4; ++j)
      slice[(g0 + lg * 4 + j) * NFT + f] = acc[ni][j];
  }
}

// ---------------- loss3 pieces: dot(Ag,Ar), |Ag|^2, |Ar|^2 (single block)
__global__ void l3_kernel(const float* __restrict__ Ag, const float* __restrict__ Ar,
                          float* __restrict__ accv) {
  int t = threadIdx.x;
  float d = 0.f, na = 0.f, nr = 0.f;
  for (int i = t; i < NF * NF; i += 256) {
    float a = Ag[i], r = Ar[i];
    d = fmaf(a, r, d); na = fmaf(a, a, na); nr = fmaf(r, r, nr);
  }
  #pragma unroll
  for (int off = 32; off > 0; off >>= 1) {
    d += __shfl_xor(d, off); na += __shfl_xor(na, off); nr += __shfl_xor(nr, off);
  }
  __shared__ float r3[3][4];
  int lane = t & 63, w = t >> 6;
  if (lane == 0) { r3[0][w] = d; r3[1][w] = na; r3[2][w] = nr; }
  __syncthreads();
  if (t == 0) {
    accv[2] = r3[0][0] + r3[0][1] + r3[0][2] + r3[0][3];
    accv[3] = r3[1][0] + r3[1][1] + r3[1][2] + r3[1][3];
    accv[4] = r3[2][0] + r3[2][1] + r3[2][2] + r3[2][3];
  }
}

// ---------------- loss4 pieces: dot(Sg,ASr), |Sg|^2, |ASr|^2 (sums KSPLIT slices)
__global__ void l4red_kernel(const unsigned short* __restrict__ Sgbf,
                             const float* __restrict__ ASr5,
                             float* __restrict__ accv) {
  int t = blockIdx.x * blockDim.x + threadIdx.x;
  float d = 0.f, n1 = 0.f, n2 = 0.f;
  for (int idx = t; idx < N_GENES * NFT; idx += gridDim.x * blockDim.x) {
    int g = idx / NFT, f = idx - g * NFT;
    float av = 0.f;
    #pragma unroll
    for (int s = 0; s < KSPLIT; ++s) av += ASr5[(long)s * (N_GENES * NFT) + idx];
    float sg = bf2f(Sgbf[g * KP + f]);
    d = fmaf(sg, av, d); n1 = fmaf(sg, sg, n1); n2 = fmaf(av, av, n2);
  }
  #pragma unroll
  for (int off = 32; off > 0; off >>= 1) {
    d += __shfl_xor(d, off); n1 += __shfl_xor(n1, off); n2 += __shfl_xor(n2, off);
  }
  __shared__ float r3[3][4];
  int lane = threadIdx.x & 63, w = threadIdx.x >> 6;
  if (lane == 0) { r3[0][w] = d; r3[1][w] = n1; r3[2][w] = n2; }
  __syncthreads();
  if (threadIdx.x == 0) {
    atomicAdd(&accv[5], r3[0][0] + r3[0][1] + r3[0][2] + r3[0][3]);
    atomicAdd(&accv[6], r3[1][0] + r3[1][1] + r3[1][2] + r3[1][3]);
    atomicAdd(&accv[7], r3[2][0] + r3[2][1] + r3[2][2] + r3[2][3]);
  }
}

// ---------------- finalize
__global__ void fin_kernel(const float* __restrict__ accv,
                           const float* __restrict__ bk1,
                           const float* __restrict__ bk2,
                           const float* __restrict__ alpha,
                           float* __restrict__ out) {
  if (threadIdx.x == 0) {
    float s1 = 0.f, s2 = 0.f;
    for (int i = 0; i < 64; ++i) { s1 += bk1[i]; s2 += bk2[i]; }
    float loss1 = s1 / 64000000.0f;
    float loss2 = s2 / 160000000.0f;
    float loss3 = -accv[2] / (sqrtf(accv[3]) * sqrtf(accv[4]));
    float loss4 = -accv[5] / (sqrtf(accv[6]) * sqrtf(accv[7]));
    float l1 = alpha[0] * loss1, l2 = alpha[1] * loss2;
    float l3 = alpha[2] * loss3, l4 = alpha[3] * loss4;
    out[0] = l1 + l2 + l3 + l4;
    out[1] = l1; out[2] = l2; out[3] = l3; out[4] = l4;
  }
}

// ws layout (bytes):
//   0         : accv f32[16]                       (64)
//   64        : buckets1 f32[64]                   (256)
//   320       : buckets2 f32[64]                   (256)
//   1024      : ASr5 f32 [5][8000][112]            (17,920,000)
//   17,921,024: T1 bf16 [8000][128]                (2,048,000)
//   19,969,024: T2 bf16 [8000][128]                (2,048,000)
//   22,017,024: Sg bf16 [8000][128]                (2,048,000)
//   24,065,024: Sr bf16 [20000][128]               (5,120,000)
//   29,185,024: SrT bf16 [112][20000]              (4,480,000)
//   total ~33.7 MB

extern "C" void kernel_launch(void* const* d_in, const int* in_sizes, int n_in,
                              void* d_out, int out_size, void* d_ws, size_t ws_size,
                              hipStream_t stream) {
  const float* G  = (const float*)d_in[0];
  const float* R  = (const float*)d_in[1];
  const float* A  = (const float*)d_in[2];
  const float* C1 = (const float*)d_in[3];
  const float* C2 = (const float*)d_in[4];
  const float* Cg = (const float*)d_in[5];
  const float* Cr = (const float*)d_in[6];
  const float* Ag = (const float*)d_in[7];
  const float* Ar = (const float*)d_in[8];
  const float* bg = (const float*)d_in[9];
  const float* br = (const float*)d_in[10];
  const float* b1 = (const float*)d_in[11];
  const float* b2 = (const float*)d_in[12];
  const float* alpha = (const float*)d_in[13];

  char* ws = (char*)d_ws;
  float* accv           = (float*)(ws + 0);
  float* buckets1       = (float*)(ws + 64);
  float* buckets2       = (float*)(ws + 320);
  float* ASr5           = (float*)(ws + 1024);
  unsigned short* T1    = (unsigned short*)(ws + 17921024);
  unsigned short* T2    = (unsigned short*)(ws + 19969024);
  unsigned short* Sg    = (unsigned short*)(ws + 22017024);
  unsigned short* Sr    = (unsigned short*)(ws + 24065024);
  unsigned short* SrT   = (unsigned short*)(ws + 29185024);

  hipMemsetAsync(d_ws, 0, 576, stream);  // accv + buckets only

  softmax_matT_kernel<<<N_CELLS, 128, 0, stream>>>(C1, Ag, T1);
  softmax_matT_kernel<<<N_CELLS, 128, 0, stream>>>(C2, Ar, T2);
  softmax_kernel<<<N_GENES, 128, 0, stream>>>(Cg, Sg, (unsigned short*)nullptr, 0);
  softmax_kernel<<<N_REG, 128, 0, stream>>>(Cr, Sr, SrT, N_REG);

  resid_kernel<<<dim3(63, 125), 256, 0, stream>>>(G, T1, Sg, bg, b1, N_GENES, buckets1);
  resid_kernel<<<dim3(157, 125), 256, 0, stream>>>(R, T2, Sr, br, b2, N_REG, buckets2);

  asr_kernel<<<dim3(250, KSPLIT), 128, 0, stream>>>(A, SrT, ASr5);

  l3_kernel<<<1, 256, 0, stream>>>(Ag, Ar, accv);
  l4red_kernel<<<256, 256, 0, stream>>>(Sg, ASr5, accv);
  fin_kernel<<<1, 64, 0, stream>>>(accv, buckets1, buckets2, alpha, (float*)d_out);
}

// Round 5
// 724.947 us; speedup vs baseline: 1.2817x; 1.2817x over previous
//
#include <hip/hip_runtime.h>

typedef __bf16 bf16x8 __attribute__((ext_vector_type(8)));
typedef float  f32x4  __attribute__((ext_vector_type(4)));
typedef unsigned short us4 __attribute__((ext_vector_type(4)));

#define N_CELLS 8000
#define N_GENES 8000
#define N_REG   20000
#define NF      100
#define KP      128     // padded K (factors) for MFMA
#define NFT     112     // padded factor count for ASr output (7*16)
#define KSPLIT  5       // split-K slices for ASr (125 k-steps of 32 each)

static __device__ __forceinline__ unsigned short f2bf_bits(float f) {
  unsigned u = __builtin_bit_cast(unsigned, f);
  u = (u + 0x7FFFu + ((u >> 16) & 1u)) >> 16;   // RNE
  return (unsigned short)u;
}
static __device__ __forceinline__ __bf16 f2bf(float f) {
  unsigned short h = f2bf_bits(f);
  return __builtin_bit_cast(__bf16, h);
}
static __device__ __forceinline__ float bf2f(unsigned short s) {
  unsigned u = ((unsigned)s) << 16;
  return __builtin_bit_cast(float, u);
}
static __device__ __forceinline__ bf16x8 cvt8(f32x4 v0, f32x4 v1) {
  bf16x8 r;
  r[0]=f2bf(v0[0]); r[1]=f2bf(v0[1]); r[2]=f2bf(v0[2]); r[3]=f2bf(v0[3]);
  r[4]=f2bf(v1[0]); r[5]=f2bf(v1[1]); r[6]=f2bf(v1[2]); r[7]=f2bf(v1[3]);
  return r;
}

// ---------------- fused pre-pass: all 4 softmaxes (+matvec for T1/T2) + loss3.
// One 64-lane wave per row: shuffle reduces, no barriers in softmax.
// blocks: [0,8000) C1->T1, [8000,16000) C2->T2, [16000,24000) Cg->Sg,
//         [24000,44000) Cr->Sr+SrT, 44000 = loss3.
__global__ __launch_bounds__(64) void pre_kernel(
    const float* __restrict__ C1, const float* __restrict__ C2,
    const float* __restrict__ Cg, const float* __restrict__ Cr,
    const float* __restrict__ Ag, const float* __restrict__ Ar,
    unsigned short* __restrict__ T1, unsigned short* __restrict__ T2,
    unsigned short* __restrict__ Sg, unsigned short* __restrict__ Sr,
    unsigned short* __restrict__ SrT,
    float* __restrict__ accv) {
  __shared__ float srow[NF];
  int b = blockIdx.x, t = threadIdx.x;
  if (b >= 44000) {            // loss3: dot(Ag,Ar), |Ag|^2, |Ar|^2
    float d = 0.f, na = 0.f, nr = 0.f;
    for (int i = t; i < NF * NF; i += 64) {
      float a = Ag[i], r = Ar[i];
      d = fmaf(a, r, d); na = fmaf(a, a, na); nr = fmaf(r, r, nr);
    }
    #pragma unroll
    for (int off = 32; off > 0; off >>= 1) {
      d += __shfl_xor(d, off); na += __shfl_xor(na, off); nr += __shfl_xor(nr, off);
    }
    if (t == 0) { accv[2] = d; accv[3] = na; accv[4] = nr; }
    return;
  }
  const float* C; const float* W = nullptr;
  unsigned short* outR = nullptr; unsigned short* outT = nullptr;
  bool isSr = false;
  int i;
  if (b < 8000)       { C = C1; W = Ag; outT = T1; i = b; }
  else if (b < 16000) { C = C2; W = Ar; outT = T2; i = b - 8000; }
  else if (b < 24000) { C = Cg; outR = Sg; i = b - 16000; }
  else                { C = Cr; outR = Sr; isSr = true; i = b - 24000; }

  // row softmax over 100 elems: lane t holds elem t and (t<36) elem 64+t
  float v0 = C[i * NF + t];
  float v1 = (t < 36) ? C[i * NF + 64 + t] : -3.0e38f;
  float m = fmaxf(v0, v1);
  #pragma unroll
  for (int off = 32; off > 0; off >>= 1) m = fmaxf(m, __shfl_xor(m, off));
  float e0 = __expf(v0 - m);
  float e1 = (t < 36) ? __expf(v1 - m) : 0.f;
  float s = e0 + e1;
  #pragma unroll
  for (int off = 32; off > 0; off >>= 1) s += __shfl_xor(s, off);
  float inv = 1.f / s;
  e0 *= inv; e1 *= inv;

  if (outT == nullptr) {
    unsigned short b0 = f2bf_bits(e0);
    unsigned short b1 = (t < 36) ? f2bf_bits(e1) : (unsigned short)0;
    outR[i * KP + t] = b0;
    outR[i * KP + 64 + t] = b1;
    if (isSr) {
      SrT[t * N_REG + i] = b0;
      if (t < 48) SrT[(64 + t) * N_REG + i] = b1;   // rows 100..111 get zeros
    }
    return;
  }
  // T = srow @ W  (each lane: output cols t and 64+t)
  srow[t] = e0;
  if (t < 36) srow[64 + t] = e1;
  __syncthreads();
  int c2 = 64 + t;
  int c2c = (c2 < NF) ? c2 : NF - 1;     // clamped; masked at write
  float a0=0.f, a1=0.f, a2=0.f, a3=0.f;
  float d0=0.f, d1=0.f, d2=0.f, d3=0.f;
  #pragma unroll 4
  for (int k = 0; k < NF; k += 4) {
    float s0 = srow[k], s1 = srow[k+1], s2 = srow[k+2], s3 = srow[k+3];
    a0 = fmaf(s0, W[(k  )*NF + t], a0);
    a1 = fmaf(s1, W[(k+1)*NF + t], a1);
    a2 = fmaf(s2, W[(k+2)*NF + t], a2);
    a3 = fmaf(s3, W[(k+3)*NF + t], a3);
    d0 = fmaf(s0, W[(k  )*NF + c2c], d0);
    d1 = fmaf(s1, W[(k+1)*NF + c2c], d1);
    d2 = fmaf(s2, W[(k+2)*NF + c2c], d2);
    d3 = fmaf(s3, W[(k+3)*NF + c2c], d3);
  }
  outT[i * KP + t]  = f2bf_bits((a0 + a1) + (a2 + a3));
  outT[i * KP + c2] = (c2 < NF) ? f2bf_bits((d0 + d1) + (d2 + d3)) : (unsigned short)0;
}

// ---------------- fused residual SSE: sum((X - Tm@Sm^T - bcol - brow)^2)
// LDS-staged panels (48 KB: Tm 64x128, Sm 128x128 bf16) with XOR swizzle
// (byte ^= (row&7)<<4) so ds_read_b128 fragment reads are conflict-free.
// X float4 loads issued after staging loads -> stay in flight across K-loop.
// Epilogue mapping verified in round 4 (absmax 0).
__global__ __launch_bounds__(256, 3) void resid_kernel(
    const float* __restrict__ X,
    const unsigned short* __restrict__ Tm,   // [8000][128] bf16 (X-row panels)
    const unsigned short* __restrict__ Sm,   // [N][128]    bf16 (X-col panels)
    const float* __restrict__ bcol,
    const float* __restrict__ brow,
    int N, float* __restrict__ buckets) {
  __shared__ char ldsbuf[49152];
  char* ldsT = ldsbuf;            // [64][256B]  swizzled
  char* ldsS = ldsbuf + 16384;    // [128][256B] swizzled
  int t = threadIdx.x;
  int wid = t >> 6, lane = t & 63;
  int lr = lane & 15, lg = lane >> 4;
  long r0blk = (long)blockIdx.y * 64;
  long c0blk = (long)blockIdx.x * 128;
  int r0 = (wid >> 1) * 32;       // wave row offset within block
  int c0 = (wid & 1) * 64;        // wave col offset within block

  // ---- panel staging loads (L2-resident) issue first
  bf16x8 sT[4], sS[8];
  #pragma unroll
  for (int i2 = 0; i2 < 4; ++i2) {
    int g = i2 * 256 + t, row = g >> 4, gi = g & 15;
    sT[i2] = *reinterpret_cast<const bf16x8*>(Tm + (r0blk + row) * KP + gi * 8);
  }
  #pragma unroll
  for (int i2 = 0; i2 < 8; ++i2) {
    int g = i2 * 256 + t, row = g >> 4, gi = g & 15;
    sS[i2] = *reinterpret_cast<const bf16x8*>(Sm + (c0blk + row) * KP + gi * 8);
  }

  // ---- streaming X loads (HBM): issued now, consumed only in epilogue
  f32x4 xv[2][4];
  #pragma unroll
  for (int ri = 0; ri < 2; ++ri) {
    long row = r0blk + r0 + ri * 16 + lr;
    #pragma unroll
    for (int ci = 0; ci < 4; ++ci) {
      long cb = c0blk + c0 + ci * 16 + lg * 4;
      if (cb < N) xv[ri][ci] = *reinterpret_cast<const f32x4*>(X + row * N + cb);
      else        xv[ri][ci] = f32x4{0.f, 0.f, 0.f, 0.f};
    }
  }

  // ---- swizzled LDS writes (wait only on staging loads; X stays in flight)
  #pragma unroll
  for (int i2 = 0; i2 < 4; ++i2) {
    int g = i2 * 256 + t, row = g >> 4, gi = g & 15;
    int off = row * 256 + ((gi * 16) ^ ((row & 7) << 4));
    *reinterpret_cast<bf16x8*>(ldsT + off) = sT[i2];
  }
  #pragma unroll
  for (int i2 = 0; i2 < 8; ++i2) {
    int g = i2 * 256 + t, row = g >> 4, gi = g & 15;
    int off = row * 256 + ((gi * 16) ^ ((row & 7) << 4));
    *reinterpret_cast<bf16x8*>(ldsS + off) = sS[i2];
  }
  __syncthreads();

  // ---- K-loop from LDS: MFMA A = Sm cols, B = Tm rows, acc[ci][ri]
  f32x4 zero = {0.f, 0.f, 0.f, 0.f};
  f32x4 acc[4][2] = {{zero, zero}, {zero, zero}, {zero, zero}, {zero, zero}};
  #pragma unroll
  for (int ks = 0; ks < 4; ++ks) {
    bf16x8 a[4], bfr[2];
    #pragma unroll
    for (int ci = 0; ci < 4; ++ci) {
      int row = c0 + ci * 16 + lr;
      int off = row * 256 + (((ks * 64) + (lg * 16)) ^ ((row & 7) << 4));
      a[ci] = *reinterpret_cast<const bf16x8*>(ldsS + off);
    }
    #pragma unroll
    for (int ri = 0; ri < 2; ++ri) {
      int row = r0 + ri * 16 + lr;
      int off = row * 256 + (((ks * 64) + (lg * 16)) ^ ((row & 7) << 4));
      bfr[ri] = *reinterpret_cast<const bf16x8*>(ldsT + off);
    }
    #pragma unroll
    for (int ci = 0; ci < 4; ++ci)
      #pragma unroll
      for (int ri = 0; ri < 2; ++ri)
        acc[ci][ri] = __builtin_amdgcn_mfma_f32_16x16x32_bf16(a[ci], bfr[ri], acc[ci][ri], 0, 0, 0);
  }

  // ---- epilogue: D m-index = X-col (lg*4+j), n-index = X-row (lr)
  float brv[2];
  #pragma unroll
  for (int ri = 0; ri < 2; ++ri) brv[ri] = brow[r0blk + r0 + ri * 16 + lr];

  float sse = 0.f;
  #pragma unroll
  for (int ci = 0; ci < 4; ++ci) {
    long cb = c0blk + c0 + ci * 16 + lg * 4;
    if (cb < N) {
      f32x4 bc = *reinterpret_cast<const f32x4*>(bcol + cb);
      #pragma unroll
      for (int ri = 0; ri < 2; ++ri) {
        f32x4 x = xv[ri][ci];
        #pragma unroll
        for (int j = 0; j < 4; ++j) {
          float e = x[j] - acc[ci][ri][j] - bc[j] - brv[ri];
          sse = fmaf(e, e, sse);
        }
      }
    }
  }
  #pragma unroll
  for (int off = 32; off > 0; off >>= 1) sse += __shfl_xor(sse, off);
  __shared__ float wsum[4];
  if (lane == 0) wsum[wid] = sse;
  __syncthreads();
  if (t == 0)
    atomicAdd(&buckets[(blockIdx.y * gridDim.x + blockIdx.x) & 63],
              wsum[0] + wsum[1] + wsum[2] + wsum[3]);
}

// ---------------- ASr = A(f32,[8000][20000]) @ Sr via SrT bf16 [112][20000]
// split-K=5, plain stores; software-pipelined (even/odd prefetch depth 1) so
// A (HBM) and SrT (L2) loads for step k+1 fly during step k's MFMAs.
// grid (250, 5): 250 blocks * 32 genes = 8000.
__global__ __launch_bounds__(128) void asr_kernel(
    const float* __restrict__ A,
    const unsigned short* __restrict__ SrT,
    float* __restrict__ ASr5) {
  int t = threadIdx.x;
  int w = t >> 6, lane = t & 63;
  int lr = lane & 15, lg = lane >> 4;
  int g0 = blockIdx.x * 32 + w * 16;
  int kbase = blockIdx.y * (N_REG / KSPLIT);

  const float* pa = A + (long)(g0 + lr) * N_REG + kbase + lg * 8;
  const unsigned short* pb = SrT + (long)lr * N_REG + kbase + lg * 8;

  f32x4 zero = {0.f, 0.f, 0.f, 0.f};
  f32x4 acc[7] = {zero, zero, zero, zero, zero, zero, zero};
  bf16x8 be[7], bo[7];

  f32x4 a0e = *reinterpret_cast<const f32x4*>(pa);
  f32x4 a1e = *reinterpret_cast<const f32x4*>(pa + 4);
  #pragma unroll
  for (int ni = 0; ni < 7; ++ni)
    be[ni] = *reinterpret_cast<const bf16x8*>(pb + ni * 16 * N_REG);

  #pragma unroll 1
  for (int ks = 0; ks < 124; ks += 2) {
    // prefetch odd step ks+1
    f32x4 a0o = *reinterpret_cast<const f32x4*>(pa + (ks + 1) * 32);
    f32x4 a1o = *reinterpret_cast<const f32x4*>(pa + (ks + 1) * 32 + 4);
    #pragma unroll
    for (int ni = 0; ni < 7; ++ni)
      bo[ni] = *reinterpret_cast<const bf16x8*>(pb + ni * 16 * N_REG + (ks + 1) * 32);
    // compute even step ks
    {
      bf16x8 a = cvt8(a0e, a1e);
      #pragma unroll
      for (int ni = 0; ni < 7; ++ni)
        acc[ni] = __builtin_amdgcn_mfma_f32_16x16x32_bf16(a, be[ni], acc[ni], 0, 0, 0);
    }
    // prefetch even step ks+2
    a0e = *reinterpret_cast<const f32x4*>(pa + (ks + 2) * 32);
    a1e = *reinterpret_cast<const f32x4*>(pa + (ks + 2) * 32 + 4);
    #pragma unroll
    for (int ni = 0; ni < 7; ++ni)
      be[ni] = *reinterpret_cast<const bf16x8*>(pb + ni * 16 * N_REG + (ks + 2) * 32);
    // compute odd step ks+1
    {
      bf16x8 a = cvt8(a0o, a1o);
      #pragma unroll
      for (int ni = 0; ni < 7; ++ni)
        acc[ni] = __builtin_amdgcn_mfma_f32_16x16x32_bf16(a, bo[ni], acc[ni], 0, 0, 0);
    }
  }
  // final step 124 (loaded by last iteration's even prefetch)
  {
    bf16x8 a = cvt8(a0e, a1e);
    #pragma unroll
    for (int ni = 0; ni < 7; ++ni)
      acc[ni] = __builtin_amdgcn_mfma_f32_16x16x32_bf16(a, be[ni], acc[ni], 0, 0, 0);
  }

  // D: row(m=gene) = lg*4+j, col(n=factor) = ni*16+lr
  float* slice = ASr5 + (long)blockIdx.y * (N_GENES * NFT);
  #pragma unroll
  for (int ni = 0; ni < 7; ++ni) {
    int f = ni * 16 + lr;
    #pragma unroll
    for (int j = 0; j < 4; ++j)
      slice[(g0 + lg * 4 + j) * NFT + f] = acc[ni][j];
  }
}

// ---------------- loss4 pieces: dot(Sg,ASr), |Sg|^2, |ASr|^2 (sums 5 slices, vec4)
__global__ void l4red_kernel(const unsigned short* __restrict__ Sgbf,
                             const float* __restrict__ ASr5,
                             float* __restrict__ accv) {
  const int NV = N_GENES * NFT / 4;   // 224000 float4 groups
  int t = blockIdx.x * blockDim.x + threadIdx.x;
  float d = 0.f, n1 = 0.f, n2 = 0.f;
  for (int q = t; q < NV; q += gridDim.x * blockDim.x) {
    int g = q / (NFT / 4);
    int f4 = (q - g * (NFT / 4)) * 4;
    f32x4 av = {0.f, 0.f, 0.f, 0.f};
    #pragma unroll
    for (int s = 0; s < KSPLIT; ++s)
      av += *reinterpret_cast<const f32x4*>(ASr5 + (long)s * (N_GENES * NFT) + g * NFT + f4);
    us4 sgb = *reinterpret_cast<const us4*>(Sgbf + g * KP + f4);
    #pragma unroll
    for (int j = 0; j < 4; ++j) {
      float sg = bf2f(sgb[j]);
      d = fmaf(sg, av[j], d); n1 = fmaf(sg, sg, n1); n2 = fmaf(av[j], av[j], n2);
    }
  }
  #pragma unroll
  for (int off = 32; off > 0; off >>= 1) {
    d += __shfl_xor(d, off); n1 += __shfl_xor(n1, off); n2 += __shfl_xor(n2, off);
  }
  __shared__ float r3[3][4];
  int lane = threadIdx.x & 63, w = threadIdx.x >> 6;
  if (lane == 0) { r3[0][w] = d; r3[1][w] = n1; r3[2][w] = n2; }
  __syncthreads();
  if (threadIdx.x == 0) {
    atomicAdd(&accv[5], r3[0][0] + r3[0][1] + r3[0][2] + r3[0][3]);
    atomicAdd(&accv[6], r3[1][0] + r3[1][1] + r3[1][2] + r3[1][3]);
    atomicAdd(&accv[7], r3[2][0] + r3[2][1] + r3[2][2] + r3[2][3]);
  }
}

// ---------------- finalize
__global__ void fin_kernel(const float* __restrict__ accv,
                           const float* __restrict__ bk1,
                           const float* __restrict__ bk2,
                           const float* __restrict__ alpha,
                           float* __restrict__ out) {
  if (threadIdx.x == 0) {
    float s1 = 0.f, s2 = 0.f;
    for (int i = 0; i < 64; ++i) { s1 += bk1[i]; s2 += bk2[i]; }
    float loss1 = s1 / 64000000.0f;
    float loss2 = s2 / 160000000.0f;
    float loss3 = -accv[2] / (sqrtf(accv[3]) * sqrtf(accv[4]));
    float loss4 = -accv[5] / (sqrtf(accv[6]) * sqrtf(accv[7]));
    float l1 = alpha[0] * loss1, l2 = alpha[1] * loss2;
    float l3 = alpha[2] * loss3, l4 = alpha[3] * loss4;
    out[0] = l1 + l2 + l3 + l4;
    out[1] = l1; out[2] = l2; out[3] = l3; out[4] = l4;
  }
}

// ws layout (bytes):
//   0         : accv f32[16]                       (64)
//   64        : buckets1 f32[64]                   (256)
//   320       : buckets2 f32[64]                   (256)
//   1024      : ASr5 f32 [5][8000][112]            (17,920,000)
//   17,921,024: T1 bf16 [8000][128]                (2,048,000)
//   19,969,024: T2 bf16 [8000][128]                (2,048,000)
//   22,017,024: Sg bf16 [8000][128]                (2,048,000)
//   24,065,024: Sr bf16 [20000][128]               (5,120,000)
//   29,185,024: SrT bf16 [112][20000]              (4,480,000)

extern "C" void kernel_launch(void* const* d_in, const int* in_sizes, int n_in,
                              void* d_out, int out_size, void* d_ws, size_t ws_size,
                              hipStream_t stream) {
  const float* G  = (const float*)d_in[0];
  const float* R  = (const float*)d_in[1];
  const float* A  = (const float*)d_in[2];
  const float* C1 = (const float*)d_in[3];
  const float* C2 = (const float*)d_in[4];
  const float* Cg = (const float*)d_in[5];
  const float* Cr = (const float*)d_in[6];
  const float* Ag = (const float*)d_in[7];
  const float* Ar = (const float*)d_in[8];
  const float* bg = (const float*)d_in[9];
  const float* br = (const float*)d_in[10];
  const float* b1 = (const float*)d_in[11];
  const float* b2 = (const float*)d_in[12];
  const float* alpha = (const float*)d_in[13];

  char* ws = (char*)d_ws;
  float* accv           = (float*)(ws + 0);
  float* buckets1       = (float*)(ws + 64);
  float* buckets2       = (float*)(ws + 320);
  float* ASr5           = (float*)(ws + 1024);
  unsigned short* T1    = (unsigned short*)(ws + 17921024);
  unsigned short* T2    = (unsigned short*)(ws + 19969024);
  unsigned short* Sg    = (unsigned short*)(ws + 22017024);
  unsigned short* Sr    = (unsigned short*)(ws + 24065024);
  unsigned short* SrT   = (unsigned short*)(ws + 29185024);

  hipMemsetAsync(d_ws, 0, 576, stream);  // accv + buckets

  pre_kernel<<<44001, 64, 0, stream>>>(C1, C2, Cg, Cr, Ag, Ar,
                                       T1, T2, Sg, Sr, SrT, accv);

  resid_kernel<<<dim3(63, 125), 256, 0, stream>>>(G, T1, Sg, bg, b1, N_GENES, buckets1);
  resid_kernel<<<dim3(157, 125), 256, 0, stream>>>(R, T2, Sr, br, b2, N_REG, buckets2);

  asr_kernel<<<dim3(250, KSPLIT), 128, 0, stream>>>(A, SrT, ASr5);

  l4red_kernel<<<128, 256, 0, stream>>>(Sg, ASr5, accv);
  fin_kernel<<<1, 64, 0, stream>>>(accv, buckets1, buckets2, alpha, (float*)d_out);
}